// Round 1
// baseline (12412.161 us; speedup 1.0000x reference)
//
#include <hip/hip_runtime.h>

#define DIM 128
#define N_ENT 100000
#define N_HE  20000

// ---------------------------------------------------------------------------
// COO scatter SpMM: y[rows[e], :] += vals[e] * x[cols[e], :]
// 32 threads per nnz, each handles 4 consecutive dims (float4 gather,
// 4 native fp32 global atomic adds).
// ---------------------------------------------------------------------------
__global__ __launch_bounds__(256) void spmm_scatter_kernel(
    const int* __restrict__ rows,
    const int* __restrict__ cols,
    const float* __restrict__ vals,
    const float* __restrict__ x,
    float* __restrict__ y,
    int nnz) {
  unsigned tid = blockIdx.x * blockDim.x + threadIdx.x;
  unsigned e = tid >> 5;
  unsigned sub = tid & 31;
  if (e >= (unsigned)nnz) return;
  int r = rows[e];
  int c = cols[e];
  float v = vals[e];
  const float4 x4 = *reinterpret_cast<const float4*>(x + (size_t)c * DIM + sub * 4);
  float* dst = y + (size_t)r * DIM + sub * 4;
  unsafeAtomicAdd(dst + 0, v * x4.x);
  unsafeAtomicAdd(dst + 1, v * x4.y);
  unsafeAtomicAdd(dst + 2, v * x4.z);
  unsafeAtomicAdd(dst + 3, v * x4.w);
}

// ---------------------------------------------------------------------------
// Fused epilogue:
//   out[i,:] = LReLU((ego[i]+side[i]) @ W1^T + b1) + LReLU((ego[i]*side[i]) @ W2^T + b2)
// side lives in d_out (accumulated there by the SpMM stages); each block reads
// its own 32 rows, then overwrites them — no cross-block hazard.
// Block: 256 threads = 32 col-groups (tx, 4 cols each) x 8 row-groups (ty, 4 rows each).
// ---------------------------------------------------------------------------
#define ROWS_PB 32
__global__ __launch_bounds__(256) void fused_epilogue_kernel(
    const float* __restrict__ ego,
    float* __restrict__ out,          // holds side on entry, result on exit
    const float* __restrict__ W1,
    const float* __restrict__ b1,
    const float* __restrict__ W2,
    const float* __restrict__ b2) {
  __shared__ float s_lds[ROWS_PB][DIM];   // ego + side
  __shared__ float p_lds[ROWS_PB][DIM];   // ego * side

  const int row0 = blockIdx.x * ROWS_PB;
  const int t = threadIdx.x;

  // Stage 32 rows: 32*128/4 = 1024 float4 loads, 4 per thread.
  for (int i = t; i < ROWS_PB * (DIM / 4); i += 256) {
    int r = i >> 5;            // 0..31
    int q = (i & 31) * 4;      // 0..124 step 4
    const float4 e4 = *reinterpret_cast<const float4*>(ego + (size_t)(row0 + r) * DIM + q);
    const float4 sd4 = *reinterpret_cast<const float4*>(out + (size_t)(row0 + r) * DIM + q);
    s_lds[r][q + 0] = e4.x + sd4.x;
    s_lds[r][q + 1] = e4.y + sd4.y;
    s_lds[r][q + 2] = e4.z + sd4.z;
    s_lds[r][q + 3] = e4.w + sd4.w;
    p_lds[r][q + 0] = e4.x * sd4.x;
    p_lds[r][q + 1] = e4.y * sd4.y;
    p_lds[r][q + 2] = e4.z * sd4.z;
    p_lds[r][q + 3] = e4.w * sd4.w;
  }
  __syncthreads();

  const int tx = t & 31;       // col group -> cols j0..j0+3
  const int ty = t >> 5;       // row group -> rows r0..r0+3
  const int j0 = tx * 4;
  const int r0 = ty * 4;

  float acc1[4][4] = {};
  float acc2[4][4] = {};

  for (int kk = 0; kk < DIM; kk += 4) {
    float4 w1[4], w2[4];
#pragma unroll
    for (int j = 0; j < 4; j++) {
      w1[j] = *reinterpret_cast<const float4*>(W1 + (size_t)(j0 + j) * DIM + kk);
      w2[j] = *reinterpret_cast<const float4*>(W2 + (size_t)(j0 + j) * DIM + kk);
    }
#pragma unroll
    for (int r = 0; r < 4; r++) {
      const float4 s4 = *reinterpret_cast<const float4*>(&s_lds[r0 + r][kk]);
      const float4 p4 = *reinterpret_cast<const float4*>(&p_lds[r0 + r][kk]);
#pragma unroll
      for (int j = 0; j < 4; j++) {
        acc1[r][j] += s4.x * w1[j].x + s4.y * w1[j].y + s4.z * w1[j].z + s4.w * w1[j].w;
        acc2[r][j] += p4.x * w2[j].x + p4.y * w2[j].y + p4.z * w2[j].z + p4.w * w2[j].w;
      }
    }
  }
  __syncthreads();

#pragma unroll
  for (int r = 0; r < 4; r++) {
#pragma unroll
    for (int j = 0; j < 4; j++) {
      float v1 = acc1[r][j] + b1[j0 + j];
      v1 = v1 > 0.0f ? v1 : 0.01f * v1;
      float v2 = acc2[r][j] + b2[j0 + j];
      v2 = v2 > 0.0f ? v2 : 0.01f * v2;
      out[(size_t)(row0 + r0 + r) * DIM + j0 + j] = v1 + v2;
    }
  }
}

// ---------------------------------------------------------------------------
// Launch
// ---------------------------------------------------------------------------
extern "C" void kernel_launch(void* const* d_in, const int* in_sizes, int n_in,
                              void* d_out, int out_size, void* d_ws, size_t ws_size,
                              hipStream_t stream) {
  const float* ego     = (const float*)d_in[0];
  const int*   A_rows  = (const int*)d_in[1];
  const int*   A_cols  = (const int*)d_in[2];
  const float* A_vals  = (const float*)d_in[3];
  const int*   p1_rows = (const int*)d_in[4];
  const int*   p1_cols = (const int*)d_in[5];
  const float* p1_vals = (const float*)d_in[6];
  const int*   p2_rows = (const int*)d_in[7];
  const int*   p2_cols = (const int*)d_in[8];
  const float* p2_vals = (const float*)d_in[9];
  const int*   l1_rows = (const int*)d_in[10];
  const int*   l1_cols = (const int*)d_in[11];
  const float* l1_vals = (const float*)d_in[12];
  const int*   l2_rows = (const int*)d_in[13];
  const int*   l2_cols = (const int*)d_in[14];
  const float* l2_vals = (const float*)d_in[15];
  const float* W1      = (const float*)d_in[16];
  const float* b1      = (const float*)d_in[17];
  const float* W2      = (const float*)d_in[18];
  const float* b2      = (const float*)d_in[19];

  const int nnz_A  = in_sizes[1];
  const int nnz_p1 = in_sizes[4];
  const int nnz_p2 = in_sizes[7];
  const int nnz_l1 = in_sizes[10];
  const int nnz_l2 = in_sizes[13];

  float* side = (float*)d_out;                 // side accumulator lives in d_out
  float* tmp1 = (float*)d_ws;                  // (N_HE, 128)
  float* tmp2 = tmp1 + (size_t)N_HE * DIM;     // (N_HE, 128)

  // Zero accumulators (async memset is graph-capture legal).
  hipMemsetAsync(d_ws, 0, (size_t)2 * N_HE * DIM * sizeof(float), stream);
  hipMemsetAsync(d_out, 0, (size_t)N_ENT * DIM * sizeof(float), stream);

  auto launch_spmm = [&](const int* r, const int* c, const float* v,
                         const float* x, float* y, int nnz) {
    const unsigned threads = (unsigned)nnz * 32u;
    const unsigned blocks = (threads + 255u) / 256u;
    spmm_scatter_kernel<<<dim3(blocks), dim3(256), 0, stream>>>(r, c, v, x, y, nnz);
  };

  // Stage 1: hyperedge aggregations
  launch_spmm(p1_rows, p1_cols, p1_vals, ego, tmp1, nnz_p1);
  launch_spmm(l1_rows, l1_cols, l1_vals, ego, tmp2, nnz_l1);

  // Stage 2: entity-side accumulation into d_out
  launch_spmm(A_rows, A_cols, A_vals, ego, side, nnz_A);
  launch_spmm(p2_rows, p2_cols, p2_vals, tmp1, side, nnz_p2);
  launch_spmm(l2_rows, l2_cols, l2_vals, tmp2, side, nnz_l2);

  // Stage 3: fused bi-interaction epilogue (in-place on d_out)
  fused_epilogue_kernel<<<dim3(N_ENT / ROWS_PB), dim3(256), 0, stream>>>(
      ego, side, W1, b1, W2, b2);
}

// Round 2
// 2792.005 us; speedup vs baseline: 4.4456x; 4.4456x over previous
//
#include <hip/hip_runtime.h>

#define DIM 128
#define N_ENT 100000
#define N_HE  20000

// ---------------------------------------------------------------------------
// CSR build: histogram -> exclusive scan (single block) -> counting-sort
// scatter of edge ids. Only int atomics (~2 per nnz).
// ---------------------------------------------------------------------------
__global__ __launch_bounds__(256) void hist_kernel(const int* __restrict__ rows,
                                                   int* __restrict__ counts, int nnz) {
  int e = blockIdx.x * 256 + threadIdx.x;
  if (e < nnz) atomicAdd(&counts[rows[e]], 1);
}

// counts (in) -> row_ptr (exclusive scan, n+1); counts overwritten with cursor copy.
__global__ __launch_bounds__(1024) void scan_kernel(int* __restrict__ counts,
                                                    int* __restrict__ row_ptr, int n) {
  __shared__ int sums[1024];
  const int t = threadIdx.x;
  const int chunk = (n + 1023) / 1024;
  const int lo = min(t * chunk, n);
  const int hi = min(lo + chunk, n);
  int s = 0;
  for (int i = lo; i < hi; i++) s += counts[i];
  sums[t] = s;
  __syncthreads();
  for (int off = 1; off < 1024; off <<= 1) {
    int v = (t >= off) ? sums[t - off] : 0;
    __syncthreads();
    sums[t] += v;
    __syncthreads();
  }
  int run = (t == 0) ? 0 : sums[t - 1];
  for (int i = lo; i < hi; i++) {
    int c = counts[i];
    row_ptr[i] = run;
    counts[i] = run;      // becomes the scatter cursor
    run += c;
  }
  if (t == 1023) row_ptr[n] = sums[1023];
}

__global__ __launch_bounds__(256) void scatter_kernel(const int* __restrict__ rows,
                                                      int* __restrict__ cursor,
                                                      int* __restrict__ perm, int nnz) {
  int e = blockIdx.x * 256 + threadIdx.x;
  if (e < nnz) {
    int p = atomicAdd(&cursor[rows[e]], 1);
    perm[p] = e;
  }
}

// ---------------------------------------------------------------------------
// CSR gather SpMM: 32-lane group per row, float4 per lane (128 dims).
// y[row,:] (+)= sum_e vals[e] * x[cols[e],:]
// ---------------------------------------------------------------------------
template <bool ADD>
__global__ __launch_bounds__(256) void csr_gather_kernel(
    const int* __restrict__ row_ptr, const int* __restrict__ perm,
    const int* __restrict__ cols, const float* __restrict__ vals,
    const float* __restrict__ x, float* __restrict__ y, int n_rows) {
  const int row = blockIdx.x * 8 + (threadIdx.x >> 5);
  const int sub = threadIdx.x & 31;
  if (row >= n_rows) return;
  const int beg = row_ptr[row];
  const int end = row_ptr[row + 1];
  float4 acc = make_float4(0.f, 0.f, 0.f, 0.f);
  int j = beg;
  for (; j + 2 <= end; j += 2) {           // 2-edge unroll for MLP
    int e0 = perm[j], e1 = perm[j + 1];
    int c0 = cols[e0], c1 = cols[e1];
    float v0 = vals[e0], v1 = vals[e1];
    float4 a4 = *reinterpret_cast<const float4*>(x + (size_t)c0 * DIM + sub * 4);
    float4 b4 = *reinterpret_cast<const float4*>(x + (size_t)c1 * DIM + sub * 4);
    acc.x += v0 * a4.x + v1 * b4.x;
    acc.y += v0 * a4.y + v1 * b4.y;
    acc.z += v0 * a4.z + v1 * b4.z;
    acc.w += v0 * a4.w + v1 * b4.w;
  }
  if (j < end) {
    int e0 = perm[j];
    int c0 = cols[e0];
    float v0 = vals[e0];
    float4 a4 = *reinterpret_cast<const float4*>(x + (size_t)c0 * DIM + sub * 4);
    acc.x += v0 * a4.x; acc.y += v0 * a4.y; acc.z += v0 * a4.z; acc.w += v0 * a4.w;
  }
  float* dst = y + (size_t)row * DIM + sub * 4;
  if (ADD) {
    float4 o = *reinterpret_cast<const float4*>(dst);
    acc.x += o.x; acc.y += o.y; acc.z += o.z; acc.w += o.w;
  }
  *reinterpret_cast<float4*>(dst) = acc;
}

// ---------------------------------------------------------------------------
// Fused epilogue (unchanged from round 1):
//   out[i,:] = LReLU((ego[i]+side[i]) @ W1^T + b1) + LReLU((ego[i]*side[i]) @ W2^T + b2)
// ---------------------------------------------------------------------------
#define ROWS_PB 32
__global__ __launch_bounds__(256) void fused_epilogue_kernel(
    const float* __restrict__ ego,
    float* __restrict__ out,
    const float* __restrict__ W1,
    const float* __restrict__ b1,
    const float* __restrict__ W2,
    const float* __restrict__ b2) {
  __shared__ float s_lds[ROWS_PB][DIM];
  __shared__ float p_lds[ROWS_PB][DIM];

  const int row0 = blockIdx.x * ROWS_PB;
  const int t = threadIdx.x;

  for (int i = t; i < ROWS_PB * (DIM / 4); i += 256) {
    int r = i >> 5;
    int q = (i & 31) * 4;
    const float4 e4 = *reinterpret_cast<const float4*>(ego + (size_t)(row0 + r) * DIM + q);
    const float4 sd4 = *reinterpret_cast<const float4*>(out + (size_t)(row0 + r) * DIM + q);
    s_lds[r][q + 0] = e4.x + sd4.x;
    s_lds[r][q + 1] = e4.y + sd4.y;
    s_lds[r][q + 2] = e4.z + sd4.z;
    s_lds[r][q + 3] = e4.w + sd4.w;
    p_lds[r][q + 0] = e4.x * sd4.x;
    p_lds[r][q + 1] = e4.y * sd4.y;
    p_lds[r][q + 2] = e4.z * sd4.z;
    p_lds[r][q + 3] = e4.w * sd4.w;
  }
  __syncthreads();

  const int tx = t & 31;
  const int ty = t >> 5;
  const int j0 = tx * 4;
  const int r0 = ty * 4;

  float acc1[4][4] = {};
  float acc2[4][4] = {};

  for (int kk = 0; kk < DIM; kk += 4) {
    float4 w1[4], w2[4];
#pragma unroll
    for (int j = 0; j < 4; j++) {
      w1[j] = *reinterpret_cast<const float4*>(W1 + (size_t)(j0 + j) * DIM + kk);
      w2[j] = *reinterpret_cast<const float4*>(W2 + (size_t)(j0 + j) * DIM + kk);
    }
#pragma unroll
    for (int r = 0; r < 4; r++) {
      const float4 s4 = *reinterpret_cast<const float4*>(&s_lds[r0 + r][kk]);
      const float4 p4 = *reinterpret_cast<const float4*>(&p_lds[r0 + r][kk]);
#pragma unroll
      for (int j = 0; j < 4; j++) {
        acc1[r][j] += s4.x * w1[j].x + s4.y * w1[j].y + s4.z * w1[j].z + s4.w * w1[j].w;
        acc2[r][j] += p4.x * w2[j].x + p4.y * w2[j].y + p4.z * w2[j].z + p4.w * w2[j].w;
      }
    }
  }
  __syncthreads();

#pragma unroll
  for (int r = 0; r < 4; r++) {
#pragma unroll
    for (int j = 0; j < 4; j++) {
      float v1 = acc1[r][j] + b1[j0 + j];
      v1 = v1 > 0.0f ? v1 : 0.01f * v1;
      float v2 = acc2[r][j] + b2[j0 + j];
      v2 = v2 > 0.0f ? v2 : 0.01f * v2;
      out[(size_t)(row0 + r0 + r) * DIM + j0 + j] = v1 + v2;
    }
  }
}

// ---------------------------------------------------------------------------
// Launch
// ---------------------------------------------------------------------------
extern "C" void kernel_launch(void* const* d_in, const int* in_sizes, int n_in,
                              void* d_out, int out_size, void* d_ws, size_t ws_size,
                              hipStream_t stream) {
  const float* ego     = (const float*)d_in[0];
  const int*   A_rows  = (const int*)d_in[1];
  const int*   A_cols  = (const int*)d_in[2];
  const float* A_vals  = (const float*)d_in[3];
  const int*   p1_rows = (const int*)d_in[4];
  const int*   p1_cols = (const int*)d_in[5];
  const float* p1_vals = (const float*)d_in[6];
  const int*   p2_rows = (const int*)d_in[7];
  const int*   p2_cols = (const int*)d_in[8];
  const float* p2_vals = (const float*)d_in[9];
  const int*   l1_rows = (const int*)d_in[10];
  const int*   l1_cols = (const int*)d_in[11];
  const float* l1_vals = (const float*)d_in[12];
  const int*   l2_rows = (const int*)d_in[13];
  const int*   l2_cols = (const int*)d_in[14];
  const float* l2_vals = (const float*)d_in[15];
  const float* W1      = (const float*)d_in[16];
  const float* b1      = (const float*)d_in[17];
  const float* W2      = (const float*)d_in[18];
  const float* b2      = (const float*)d_in[19];

  const int nnz_A  = in_sizes[1];
  const int nnz_p1 = in_sizes[4];
  const int nnz_p2 = in_sizes[7];
  const int nnz_l1 = in_sizes[10];
  const int nnz_l2 = in_sizes[13];

  // --- workspace layout ---
  float* tmp1 = (float*)d_ws;                       // N_HE*DIM
  float* tmp2 = tmp1 + (size_t)N_HE * DIM;          // N_HE*DIM
  int* ip = (int*)(tmp2 + (size_t)N_HE * DIM);

  struct Csr { int* counts; int* row_ptr; int* perm; };
  auto carve = [&](int n_rows, int nnz) {
    Csr c;
    c.counts = ip;  ip += n_rows;
    c.row_ptr = ip; ip += n_rows + 1;
    c.perm = ip;    ip += nnz;
    return c;
  };
  Csr cA  = carve(N_ENT, nnz_A);
  Csr cp1 = carve(N_HE,  nnz_p1);
  Csr cp2 = carve(N_ENT, nnz_p2);
  Csr cl1 = carve(N_HE,  nnz_l1);
  Csr cl2 = carve(N_ENT, nnz_l2);

  auto build = [&](const Csr& c, const int* rows, int n_rows, int nnz) {
    hipMemsetAsync(c.counts, 0, (size_t)n_rows * sizeof(int), stream);
    hist_kernel<<<dim3((nnz + 255) / 256), dim3(256), 0, stream>>>(rows, c.counts, nnz);
    scan_kernel<<<dim3(1), dim3(1024), 0, stream>>>(c.counts, c.row_ptr, n_rows);
    scatter_kernel<<<dim3((nnz + 255) / 256), dim3(256), 0, stream>>>(rows, c.counts, c.perm, nnz);
  };

  build(cA,  A_rows,  N_ENT, nnz_A);
  build(cp1, p1_rows, N_HE,  nnz_p1);
  build(cp2, p2_rows, N_ENT, nnz_p2);
  build(cl1, l1_rows, N_HE,  nnz_l1);
  build(cl2, l2_rows, N_ENT, nnz_l2);

  auto gather = [&](const Csr& c, const int* cols, const float* vals,
                    const float* x, float* y, int n_rows, bool add) {
    dim3 grid((n_rows + 7) / 8);
    if (add)
      csr_gather_kernel<true><<<grid, dim3(256), 0, stream>>>(c.row_ptr, c.perm, cols, vals, x, y, n_rows);
    else
      csr_gather_kernel<false><<<grid, dim3(256), 0, stream>>>(c.row_ptr, c.perm, cols, vals, x, y, n_rows);
  };

  float* side = (float*)d_out;

  // Stage 1: hyperedge aggregations (overwrite tmp1/tmp2)
  gather(cp1, p1_cols, p1_vals, ego, tmp1, N_HE, false);
  gather(cl1, l1_cols, l1_vals, ego, tmp2, N_HE, false);

  // Stage 2: entity side accumulation into d_out (A writes, p2/l2 add)
  gather(cA,  A_cols,  A_vals,  ego,  side, N_ENT, false);
  gather(cp2, p2_cols, p2_vals, tmp1, side, N_ENT, true);
  gather(cl2, l2_cols, l2_vals, tmp2, side, N_ENT, true);

  // Stage 3: fused bi-interaction epilogue (in-place on d_out)
  fused_epilogue_kernel<<<dim3(N_ENT / ROWS_PB), dim3(256), 0, stream>>>(
      ego, side, W1, b1, W2, b2);
}

// Round 3
// 1681.841 us; speedup vs baseline: 7.3801x; 1.6601x over previous
//
#include <hip/hip_runtime.h>

#define DIM 128
#define N_ENT 100000
#define N_HE  20000

// ---------------------------------------------------------------------------
// CSR build: histogram -> fused 5-way in-place exclusive scan -> counting-sort
// scatter producing sorted (col, val) int2 pairs. Only int atomics.
// After scatter, cur[] holds END offsets; beg(row) = row ? cur[row-1] : 0.
// ---------------------------------------------------------------------------
__global__ __launch_bounds__(256) void hist_kernel(const int* __restrict__ rows,
                                                   int* __restrict__ cnt, int nnz) {
  int e = blockIdx.x * 256 + threadIdx.x;
  if (e < nnz) atomicAdd(&cnt[rows[e]], 1);
}

__global__ __launch_bounds__(1024) void scan5_kernel(int* c0, int n0, int* c1, int n1,
                                                     int* c2, int n2, int* c3, int n3,
                                                     int* c4, int n4) {
  int* c; int n;
  switch (blockIdx.x) {
    case 0: c = c0; n = n0; break;
    case 1: c = c1; n = n1; break;
    case 2: c = c2; n = n2; break;
    case 3: c = c3; n = n3; break;
    default: c = c4; n = n4; break;
  }
  __shared__ int sums[1024];
  const int t = threadIdx.x;
  const int chunk = (n + 1023) / 1024;
  const int lo = min(t * chunk, n);
  const int hi = min(lo + chunk, n);
  int s = 0;
  for (int i = lo; i < hi; i++) s += c[i];
  sums[t] = s;
  __syncthreads();
  for (int off = 1; off < 1024; off <<= 1) {
    int v = (t >= off) ? sums[t - off] : 0;
    __syncthreads();
    sums[t] += v;
    __syncthreads();
  }
  int run = t ? sums[t - 1] : 0;
  for (int i = lo; i < hi; i++) { int v = c[i]; c[i] = run; run += v; }
}

__global__ __launch_bounds__(256) void scatter_kernel(const int* __restrict__ rows,
                                                      const int* __restrict__ cols,
                                                      const float* __restrict__ vals,
                                                      int* __restrict__ cur,
                                                      int2* __restrict__ colv, int nnz) {
  int e = blockIdx.x * 256 + threadIdx.x;
  if (e < nnz) {
    int p = atomicAdd(&cur[rows[e]], 1);
    colv[p] = make_int2(cols[e], __float_as_int(vals[e]));
  }
}

// ---------------------------------------------------------------------------
// Row accumulate: acc += sum_j vals[j] * x[cols[j], sub*4 .. sub*4+3]
// 4-edge unroll -> 4 independent gathers in flight per lane.
// ---------------------------------------------------------------------------
__device__ __forceinline__ void row_accum(const int* __restrict__ cur,
                                          const int2* __restrict__ colv,
                                          const float* __restrict__ x,
                                          int row, int sub, float4& acc) {
  const int beg = row ? cur[row - 1] : 0;
  const int end = cur[row];
  int j = beg;
  for (; j + 4 <= end; j += 4) {
    int2 c0 = colv[j], c1 = colv[j + 1], c2 = colv[j + 2], c3 = colv[j + 3];
    float4 a0 = *reinterpret_cast<const float4*>(x + (size_t)c0.x * DIM + sub * 4);
    float4 a1 = *reinterpret_cast<const float4*>(x + (size_t)c1.x * DIM + sub * 4);
    float4 a2 = *reinterpret_cast<const float4*>(x + (size_t)c2.x * DIM + sub * 4);
    float4 a3 = *reinterpret_cast<const float4*>(x + (size_t)c3.x * DIM + sub * 4);
    float v0 = __int_as_float(c0.y), v1 = __int_as_float(c1.y);
    float v2 = __int_as_float(c2.y), v3 = __int_as_float(c3.y);
    acc.x = fmaf(v0, a0.x, acc.x); acc.y = fmaf(v0, a0.y, acc.y);
    acc.z = fmaf(v0, a0.z, acc.z); acc.w = fmaf(v0, a0.w, acc.w);
    acc.x = fmaf(v1, a1.x, acc.x); acc.y = fmaf(v1, a1.y, acc.y);
    acc.z = fmaf(v1, a1.z, acc.z); acc.w = fmaf(v1, a1.w, acc.w);
    acc.x = fmaf(v2, a2.x, acc.x); acc.y = fmaf(v2, a2.y, acc.y);
    acc.z = fmaf(v2, a2.z, acc.z); acc.w = fmaf(v2, a2.w, acc.w);
    acc.x = fmaf(v3, a3.x, acc.x); acc.y = fmaf(v3, a3.y, acc.y);
    acc.z = fmaf(v3, a3.z, acc.z); acc.w = fmaf(v3, a3.w, acc.w);
  }
  for (; j < end; j++) {
    int2 c0 = colv[j];
    float4 a0 = *reinterpret_cast<const float4*>(x + (size_t)c0.x * DIM + sub * 4);
    float v0 = __int_as_float(c0.y);
    acc.x = fmaf(v0, a0.x, acc.x); acc.y = fmaf(v0, a0.y, acc.y);
    acc.z = fmaf(v0, a0.z, acc.z); acc.w = fmaf(v0, a0.w, acc.w);
  }
}

// Stage 1: tmp1 = p1 @ ego, tmp2 = l1 @ ego  (rows in [0, N_HE))
__global__ __launch_bounds__(256) void gather_he_kernel(
    const int* __restrict__ curp1, const int2* __restrict__ cvp1,
    const int* __restrict__ curl1, const int2* __restrict__ cvl1,
    const float* __restrict__ ego, float* __restrict__ tmp1, float* __restrict__ tmp2) {
  const int row = blockIdx.x * 8 + (threadIdx.x >> 5);
  const int sub = threadIdx.x & 31;
  if (row >= N_HE) return;
  float4 a = make_float4(0.f, 0.f, 0.f, 0.f);
  float4 b = make_float4(0.f, 0.f, 0.f, 0.f);
  row_accum(curp1, cvp1, ego, row, sub, a);
  row_accum(curl1, cvl1, ego, row, sub, b);
  *reinterpret_cast<float4*>(tmp1 + (size_t)row * DIM + sub * 4) = a;
  *reinterpret_cast<float4*>(tmp2 + (size_t)row * DIM + sub * 4) = b;
}

// Stage 2: side = A @ ego + p2 @ tmp1 + l2 @ tmp2  (rows in [0, N_ENT)), one write.
__global__ __launch_bounds__(256) void gather_ent_kernel(
    const int* __restrict__ curA,  const int2* __restrict__ cvA,
    const int* __restrict__ curp2, const int2* __restrict__ cvp2,
    const int* __restrict__ curl2, const int2* __restrict__ cvl2,
    const float* __restrict__ ego, const float* __restrict__ tmp1,
    const float* __restrict__ tmp2, float* __restrict__ side) {
  const int row = blockIdx.x * 8 + (threadIdx.x >> 5);
  const int sub = threadIdx.x & 31;
  if (row >= N_ENT) return;
  float4 a = make_float4(0.f, 0.f, 0.f, 0.f);
  row_accum(curA,  cvA,  ego,  row, sub, a);
  row_accum(curp2, cvp2, tmp1, row, sub, a);
  row_accum(curl2, cvl2, tmp2, row, sub, a);
  *reinterpret_cast<float4*>(side + (size_t)row * DIM + sub * 4) = a;
}

// ---------------------------------------------------------------------------
// Fused epilogue, 64 rows/block, 8 rows/thread:
//   out[i,:] = LReLU((ego[i]+side[i]) @ W1^T + b1) + LReLU((ego[i]*side[i]) @ W2^T + b2)
// ---------------------------------------------------------------------------
#define EROWS 64
__device__ __forceinline__ float lrelu(float v) { return v > 0.0f ? v : 0.01f * v; }

__global__ __launch_bounds__(256) void fused_epilogue_kernel(
    const float* __restrict__ ego,
    float* __restrict__ out,          // holds side on entry, result on exit
    const float* __restrict__ W1,
    const float* __restrict__ b1,
    const float* __restrict__ W2,
    const float* __restrict__ b2) {
  __shared__ float s_lds[EROWS][DIM];   // ego + side
  __shared__ float p_lds[EROWS][DIM];   // ego * side

  const int row0 = blockIdx.x * EROWS;
  const int t = threadIdx.x;

  for (int i = t; i < EROWS * (DIM / 4); i += 256) {
    int r = i >> 5;
    int q = (i & 31) * 4;
    int gr = row0 + r;
    float4 e4 = make_float4(0.f, 0.f, 0.f, 0.f);
    float4 sd4 = make_float4(0.f, 0.f, 0.f, 0.f);
    if (gr < N_ENT) {
      e4 = *reinterpret_cast<const float4*>(ego + (size_t)gr * DIM + q);
      sd4 = *reinterpret_cast<const float4*>(out + (size_t)gr * DIM + q);
    }
    s_lds[r][q + 0] = e4.x + sd4.x;
    s_lds[r][q + 1] = e4.y + sd4.y;
    s_lds[r][q + 2] = e4.z + sd4.z;
    s_lds[r][q + 3] = e4.w + sd4.w;
    p_lds[r][q + 0] = e4.x * sd4.x;
    p_lds[r][q + 1] = e4.y * sd4.y;
    p_lds[r][q + 2] = e4.z * sd4.z;
    p_lds[r][q + 3] = e4.w * sd4.w;
  }
  __syncthreads();

  const int tx = t & 31;       // col group -> cols j0..j0+3
  const int ty = t >> 5;       // row group -> rows r0..r0+7
  const int j0 = tx * 4;
  const int r0 = ty * 8;

  float acc1[8][4] = {};
  float acc2[8][4] = {};

  for (int kk = 0; kk < DIM; kk += 4) {
    float4 w1v[4], w2v[4];
#pragma unroll
    for (int j = 0; j < 4; j++) {
      w1v[j] = *reinterpret_cast<const float4*>(W1 + (size_t)(j0 + j) * DIM + kk);
      w2v[j] = *reinterpret_cast<const float4*>(W2 + (size_t)(j0 + j) * DIM + kk);
    }
#pragma unroll
    for (int r = 0; r < 8; r++) {
      const float4 s4 = *reinterpret_cast<const float4*>(&s_lds[r0 + r][kk]);
      const float4 p4 = *reinterpret_cast<const float4*>(&p_lds[r0 + r][kk]);
#pragma unroll
      for (int j = 0; j < 4; j++) {
        acc1[r][j] += s4.x * w1v[j].x + s4.y * w1v[j].y + s4.z * w1v[j].z + s4.w * w1v[j].w;
        acc2[r][j] += p4.x * w2v[j].x + p4.y * w2v[j].y + p4.z * w2v[j].z + p4.w * w2v[j].w;
      }
    }
  }

  const float4 bb1 = *reinterpret_cast<const float4*>(b1 + j0);
  const float4 bb2 = *reinterpret_cast<const float4*>(b2 + j0);
#pragma unroll
  for (int r = 0; r < 8; r++) {
    int gr = row0 + r0 + r;
    if (gr < N_ENT) {
      float4 o;
      o.x = lrelu(acc1[r][0] + bb1.x) + lrelu(acc2[r][0] + bb2.x);
      o.y = lrelu(acc1[r][1] + bb1.y) + lrelu(acc2[r][1] + bb2.y);
      o.z = lrelu(acc1[r][2] + bb1.z) + lrelu(acc2[r][2] + bb2.z);
      o.w = lrelu(acc1[r][3] + bb1.w) + lrelu(acc2[r][3] + bb2.w);
      *reinterpret_cast<float4*>(out + (size_t)gr * DIM + j0) = o;
    }
  }
}

// ---------------------------------------------------------------------------
// Launch
// ---------------------------------------------------------------------------
extern "C" void kernel_launch(void* const* d_in, const int* in_sizes, int n_in,
                              void* d_out, int out_size, void* d_ws, size_t ws_size,
                              hipStream_t stream) {
  const float* ego     = (const float*)d_in[0];
  const int*   A_rows  = (const int*)d_in[1];
  const int*   A_cols  = (const int*)d_in[2];
  const float* A_vals  = (const float*)d_in[3];
  const int*   p1_rows = (const int*)d_in[4];
  const int*   p1_cols = (const int*)d_in[5];
  const float* p1_vals = (const float*)d_in[6];
  const int*   p2_rows = (const int*)d_in[7];
  const int*   p2_cols = (const int*)d_in[8];
  const float* p2_vals = (const float*)d_in[9];
  const int*   l1_rows = (const int*)d_in[10];
  const int*   l1_cols = (const int*)d_in[11];
  const float* l1_vals = (const float*)d_in[12];
  const int*   l2_rows = (const int*)d_in[13];
  const int*   l2_cols = (const int*)d_in[14];
  const float* l2_vals = (const float*)d_in[15];
  const float* W1      = (const float*)d_in[16];
  const float* b1      = (const float*)d_in[17];
  const float* W2      = (const float*)d_in[18];
  const float* b2      = (const float*)d_in[19];

  const int nnz_A  = in_sizes[1];
  const int nnz_p1 = in_sizes[4];
  const int nnz_p2 = in_sizes[7];
  const int nnz_l1 = in_sizes[10];
  const int nnz_l2 = in_sizes[13];

  // --- workspace layout ---
  float* tmp1 = (float*)d_ws;                       // N_HE*DIM
  float* tmp2 = tmp1 + (size_t)N_HE * DIM;          // N_HE*DIM
  int2* cvA  = (int2*)(tmp2 + (size_t)N_HE * DIM);  // nnz_A
  int2* cvp1 = cvA + nnz_A;                         // nnz_p1
  int2* cvp2 = cvp1 + nnz_p1;                       // nnz_p2
  int2* cvl1 = cvp2 + nnz_p2;                       // nnz_l1
  int2* cvl2 = cvl1 + nnz_l1;                       // nnz_l2
  int* curA  = (int*)(cvl2 + nnz_l2);               // N_ENT
  int* curp1 = curA + N_ENT;                        // N_HE
  int* curp2 = curp1 + N_HE;                        // N_ENT
  int* curl1 = curp2 + N_ENT;                       // N_HE
  int* curl2 = curl1 + N_HE;                        // N_ENT
  const size_t n_cur = 3 * (size_t)N_ENT + 2 * (size_t)N_HE;

  // One memset for all counter arrays (contiguous).
  hipMemsetAsync(curA, 0, n_cur * sizeof(int), stream);

  auto hist = [&](const int* rows, int* cnt, int nnz) {
    hist_kernel<<<dim3((nnz + 255) / 256), dim3(256), 0, stream>>>(rows, cnt, nnz);
  };
  hist(A_rows,  curA,  nnz_A);
  hist(p1_rows, curp1, nnz_p1);
  hist(p2_rows, curp2, nnz_p2);
  hist(l1_rows, curl1, nnz_l1);
  hist(l2_rows, curl2, nnz_l2);

  scan5_kernel<<<dim3(5), dim3(1024), 0, stream>>>(curA, N_ENT, curp1, N_HE,
                                                   curp2, N_ENT, curl1, N_HE,
                                                   curl2, N_ENT);

  auto scat = [&](const int* rows, const int* cols, const float* vals,
                  int* cur, int2* colv, int nnz) {
    scatter_kernel<<<dim3((nnz + 255) / 256), dim3(256), 0, stream>>>(rows, cols, vals, cur, colv, nnz);
  };
  scat(A_rows,  A_cols,  A_vals,  curA,  cvA,  nnz_A);
  scat(p1_rows, p1_cols, p1_vals, curp1, cvp1, nnz_p1);
  scat(p2_rows, p2_cols, p2_vals, curp2, cvp2, nnz_p2);
  scat(l1_rows, l1_cols, l1_vals, curl1, cvl1, nnz_l1);
  scat(l2_rows, l2_cols, l2_vals, curl2, cvl2, nnz_l2);

  float* side = (float*)d_out;

  // Stage 1: both hyperedge aggregations in one kernel.
  gather_he_kernel<<<dim3(N_HE / 8), dim3(256), 0, stream>>>(
      curp1, cvp1, curl1, cvl1, ego, tmp1, tmp2);

  // Stage 2: side = A@ego + p2@tmp1 + l2@tmp2, single write into d_out.
  gather_ent_kernel<<<dim3(N_ENT / 8), dim3(256), 0, stream>>>(
      curA, cvA, curp2, cvp2, curl2, cvl2, ego, tmp1, tmp2, side);

  // Stage 3: fused bi-interaction epilogue (in-place on d_out).
  fused_epilogue_kernel<<<dim3((N_ENT + EROWS - 1) / EROWS), dim3(256), 0, stream>>>(
      ego, side, W1, b1, W2, b2);
}

// Round 4
// 1408.272 us; speedup vs baseline: 8.8137x; 1.1943x over previous
//
#include <hip/hip_runtime.h>

#define DIM 128
#define N_ENT 100000
#define N_HE  20000

// ---------------------------------------------------------------------------
// bf16 helpers (RNE pack, cheap unpack)
// ---------------------------------------------------------------------------
__device__ __forceinline__ unsigned bf16_rne(float x) {
  unsigned b = __float_as_uint(x);
  return (b + 0x7fffu + ((b >> 16) & 1u)) >> 16;
}
__device__ __forceinline__ unsigned pack2(float lo, float hi) {
  return bf16_rne(lo) | (bf16_rne(hi) << 16);
}

// Convert fp32 rows -> bf16 rows (grid-stride over float4 quanta).
__global__ __launch_bounds__(256) void cvt_bf16_kernel(const float* __restrict__ src,
                                                       unsigned* __restrict__ dst,  // 2 bf16 per u32
                                                       int n4) {
  for (int i = blockIdx.x * 256 + threadIdx.x; i < n4; i += gridDim.x * 256) {
    float4 v = reinterpret_cast<const float4*>(src)[i];
    uint2 p = make_uint2(pack2(v.x, v.y), pack2(v.z, v.w));
    reinterpret_cast<uint2*>(dst)[i] = p;
  }
}

// ---------------------------------------------------------------------------
// CSR build: fused 5-seg histogram -> fused 5-way scan -> fused 5-seg scatter
// producing row-sorted (col, val_f32) int2 pairs. Only int atomics.
// After scatter, cur[] holds END offsets; beg(row) = row ? cur[row-1] : 0.
// ---------------------------------------------------------------------------
struct Seg5 {
  const int* rows[5];
  const int* cols[5];
  const float* vals[5];
  int* cur[5];
  int2* colv[5];
  int blk_pfx[6];   // block-range prefix per segment
};

__device__ __forceinline__ int seg_of(const int* pfx, int b) {
  int s = 0;
  while (s < 4 && b >= pfx[s + 1]) s++;
  return s;
}

__global__ __launch_bounds__(256) void hist5_kernel(Seg5 a, int nnz0, int nnz1, int nnz2,
                                                    int nnz3, int nnz4) {
  const int nnz[5] = {nnz0, nnz1, nnz2, nnz3, nnz4};
  int s = seg_of(a.blk_pfx, (int)blockIdx.x);
  int e = (blockIdx.x - a.blk_pfx[s]) * 256 + threadIdx.x;
  if (e < nnz[s]) atomicAdd(&a.cur[s][a.rows[s][e]], 1);
}

__global__ __launch_bounds__(256) void scatter5_kernel(Seg5 a, int nnz0, int nnz1, int nnz2,
                                                       int nnz3, int nnz4) {
  const int nnz[5] = {nnz0, nnz1, nnz2, nnz3, nnz4};
  int s = seg_of(a.blk_pfx, (int)blockIdx.x);
  int e = (blockIdx.x - a.blk_pfx[s]) * 256 + threadIdx.x;
  if (e < nnz[s]) {
    int p = atomicAdd(&a.cur[s][a.rows[s][e]], 1);
    a.colv[s][p] = make_int2(a.cols[s][e], __float_as_int(a.vals[s][e]));
  }
}

__global__ __launch_bounds__(1024) void scan5_kernel(int* c0, int n0, int* c1, int n1,
                                                     int* c2, int n2, int* c3, int n3,
                                                     int* c4, int n4) {
  int* c; int n;
  switch (blockIdx.x) {
    case 0: c = c0; n = n0; break;
    case 1: c = c1; n = n1; break;
    case 2: c = c2; n = n2; break;
    case 3: c = c3; n = n3; break;
    default: c = c4; n = n4; break;
  }
  __shared__ int sums[1024];
  const int t = threadIdx.x;
  const int chunk = (n + 1023) / 1024;
  const int lo = min(t * chunk, n);
  const int hi = min(lo + chunk, n);
  int s = 0;
  for (int i = lo; i < hi; i++) s += c[i];
  sums[t] = s;
  __syncthreads();
  for (int off = 1; off < 1024; off <<= 1) {
    int v = (t >= off) ? sums[t - off] : 0;
    __syncthreads();
    sums[t] += v;
    __syncthreads();
  }
  int run = t ? sums[t - 1] : 0;
  for (int i = lo; i < hi; i++) { int v = c[i]; c[i] = run; run += v; }
}

// ---------------------------------------------------------------------------
// Row accumulate from bf16 source rows (256 B each), fp32 accumulation.
// Each 32-lane group owns one row; lane covers dims sub*4..sub*4+3 (uint2 = 4 bf16).
// ---------------------------------------------------------------------------
__device__ __forceinline__ void bf16_fma4(float4& acc, uint2 g, float v) {
  float f0 = __uint_as_float((g.x & 0xffffu) << 16);
  float f1 = __uint_as_float(g.x & 0xffff0000u);
  float f2 = __uint_as_float((g.y & 0xffffu) << 16);
  float f3 = __uint_as_float(g.y & 0xffff0000u);
  acc.x = fmaf(v, f0, acc.x);
  acc.y = fmaf(v, f1, acc.y);
  acc.z = fmaf(v, f2, acc.z);
  acc.w = fmaf(v, f3, acc.w);
}

__device__ __forceinline__ void row_accum_h(const int* __restrict__ cur,
                                            const int2* __restrict__ colv,
                                            const unsigned* __restrict__ xh,  // 2 bf16/u32, row = 64 u32
                                            int row, int sub, float4& acc) {
  const int beg = row ? cur[row - 1] : 0;
  const int end = cur[row];
  int j = beg;
  for (; j + 4 <= end; j += 4) {
    int2 c0 = colv[j], c1 = colv[j + 1], c2 = colv[j + 2], c3 = colv[j + 3];
    uint2 g0 = *reinterpret_cast<const uint2*>(xh + (size_t)c0.x * 64 + sub * 2);
    uint2 g1 = *reinterpret_cast<const uint2*>(xh + (size_t)c1.x * 64 + sub * 2);
    uint2 g2 = *reinterpret_cast<const uint2*>(xh + (size_t)c2.x * 64 + sub * 2);
    uint2 g3 = *reinterpret_cast<const uint2*>(xh + (size_t)c3.x * 64 + sub * 2);
    bf16_fma4(acc, g0, __int_as_float(c0.y));
    bf16_fma4(acc, g1, __int_as_float(c1.y));
    bf16_fma4(acc, g2, __int_as_float(c2.y));
    bf16_fma4(acc, g3, __int_as_float(c3.y));
  }
  for (; j < end; j++) {
    int2 c0 = colv[j];
    uint2 g0 = *reinterpret_cast<const uint2*>(xh + (size_t)c0.x * 64 + sub * 2);
    bf16_fma4(acc, g0, __int_as_float(c0.y));
  }
}

// Stage 1: tmp1 = p1 @ ego, tmp2 = l1 @ ego  (rows in [0, N_HE)), bf16 out.
__global__ __launch_bounds__(256) void gather_he_kernel(
    const int* __restrict__ curp1, const int2* __restrict__ cvp1,
    const int* __restrict__ curl1, const int2* __restrict__ cvl1,
    const unsigned* __restrict__ egoh, unsigned* __restrict__ tmp1h,
    unsigned* __restrict__ tmp2h) {
  const int row = blockIdx.x * 8 + (threadIdx.x >> 5);
  const int sub = threadIdx.x & 31;
  if (row >= N_HE) return;
  float4 a = make_float4(0.f, 0.f, 0.f, 0.f);
  float4 b = make_float4(0.f, 0.f, 0.f, 0.f);
  row_accum_h(curp1, cvp1, egoh, row, sub, a);
  row_accum_h(curl1, cvl1, egoh, row, sub, b);
  *reinterpret_cast<uint2*>(tmp1h + (size_t)row * 64 + sub * 2) =
      make_uint2(pack2(a.x, a.y), pack2(a.z, a.w));
  *reinterpret_cast<uint2*>(tmp2h + (size_t)row * 64 + sub * 2) =
      make_uint2(pack2(b.x, b.y), pack2(b.z, b.w));
}

// Stage 2: side = A @ ego + p2 @ tmp1 + l2 @ tmp2  (fp32 out into d_out).
__global__ __launch_bounds__(256) void gather_ent_kernel(
    const int* __restrict__ curA,  const int2* __restrict__ cvA,
    const int* __restrict__ curp2, const int2* __restrict__ cvp2,
    const int* __restrict__ curl2, const int2* __restrict__ cvl2,
    const unsigned* __restrict__ egoh, const unsigned* __restrict__ tmp1h,
    const unsigned* __restrict__ tmp2h, float* __restrict__ side) {
  const int row = blockIdx.x * 8 + (threadIdx.x >> 5);
  const int sub = threadIdx.x & 31;
  if (row >= N_ENT) return;
  float4 a = make_float4(0.f, 0.f, 0.f, 0.f);
  row_accum_h(curA,  cvA,  egoh,  row, sub, a);
  row_accum_h(curp2, cvp2, tmp1h, row, sub, a);
  row_accum_h(curl2, cvl2, tmp2h, row, sub, a);
  *reinterpret_cast<float4*>(side + (size_t)row * DIM + sub * 4) = a;
}

// ---------------------------------------------------------------------------
// Fused epilogue, 64 rows/block, 8 rows/thread (fp32 throughout):
//   out[i,:] = LReLU((ego[i]+side[i]) @ W1^T + b1) + LReLU((ego[i]*side[i]) @ W2^T + b2)
// ---------------------------------------------------------------------------
#define EROWS 64
__device__ __forceinline__ float lrelu(float v) { return v > 0.0f ? v : 0.01f * v; }

__global__ __launch_bounds__(256) void fused_epilogue_kernel(
    const float* __restrict__ ego,
    float* __restrict__ out,          // holds side on entry, result on exit
    const float* __restrict__ W1,
    const float* __restrict__ b1,
    const float* __restrict__ W2,
    const float* __restrict__ b2) {
  __shared__ float s_lds[EROWS][DIM];   // ego + side
  __shared__ float p_lds[EROWS][DIM];   // ego * side

  const int row0 = blockIdx.x * EROWS;
  const int t = threadIdx.x;

  for (int i = t; i < EROWS * (DIM / 4); i += 256) {
    int r = i >> 5;
    int q = (i & 31) * 4;
    int gr = row0 + r;
    float4 e4 = make_float4(0.f, 0.f, 0.f, 0.f);
    float4 sd4 = make_float4(0.f, 0.f, 0.f, 0.f);
    if (gr < N_ENT) {
      e4 = *reinterpret_cast<const float4*>(ego + (size_t)gr * DIM + q);
      sd4 = *reinterpret_cast<const float4*>(out + (size_t)gr * DIM + q);
    }
    s_lds[r][q + 0] = e4.x + sd4.x;
    s_lds[r][q + 1] = e4.y + sd4.y;
    s_lds[r][q + 2] = e4.z + sd4.z;
    s_lds[r][q + 3] = e4.w + sd4.w;
    p_lds[r][q + 0] = e4.x * sd4.x;
    p_lds[r][q + 1] = e4.y * sd4.y;
    p_lds[r][q + 2] = e4.z * sd4.z;
    p_lds[r][q + 3] = e4.w * sd4.w;
  }
  __syncthreads();

  const int tx = t & 31;       // col group -> cols j0..j0+3
  const int ty = t >> 5;       // row group -> rows r0..r0+7
  const int j0 = tx * 4;
  const int r0 = ty * 8;

  float acc1[8][4] = {};
  float acc2[8][4] = {};

  for (int kk = 0; kk < DIM; kk += 4) {
    float4 w1v[4], w2v[4];
#pragma unroll
    for (int j = 0; j < 4; j++) {
      w1v[j] = *reinterpret_cast<const float4*>(W1 + (size_t)(j0 + j) * DIM + kk);
      w2v[j] = *reinterpret_cast<const float4*>(W2 + (size_t)(j0 + j) * DIM + kk);
    }
#pragma unroll
    for (int r = 0; r < 8; r++) {
      const float4 s4 = *reinterpret_cast<const float4*>(&s_lds[r0 + r][kk]);
      const float4 p4 = *reinterpret_cast<const float4*>(&p_lds[r0 + r][kk]);
#pragma unroll
      for (int j = 0; j < 4; j++) {
        acc1[r][j] += s4.x * w1v[j].x + s4.y * w1v[j].y + s4.z * w1v[j].z + s4.w * w1v[j].w;
        acc2[r][j] += p4.x * w2v[j].x + p4.y * w2v[j].y + p4.z * w2v[j].z + p4.w * w2v[j].w;
      }
    }
  }

  const float4 bb1 = *reinterpret_cast<const float4*>(b1 + j0);
  const float4 bb2 = *reinterpret_cast<const float4*>(b2 + j0);
#pragma unroll
  for (int r = 0; r < 8; r++) {
    int gr = row0 + r0 + r;
    if (gr < N_ENT) {
      float4 o;
      o.x = lrelu(acc1[r][0] + bb1.x) + lrelu(acc2[r][0] + bb2.x);
      o.y = lrelu(acc1[r][1] + bb1.y) + lrelu(acc2[r][1] + bb2.y);
      o.z = lrelu(acc1[r][2] + bb1.z) + lrelu(acc2[r][2] + bb2.z);
      o.w = lrelu(acc1[r][3] + bb1.w) + lrelu(acc2[r][3] + bb2.w);
      *reinterpret_cast<float4*>(out + (size_t)gr * DIM + j0) = o;
    }
  }
}

// ---------------------------------------------------------------------------
// Launch
// ---------------------------------------------------------------------------
extern "C" void kernel_launch(void* const* d_in, const int* in_sizes, int n_in,
                              void* d_out, int out_size, void* d_ws, size_t ws_size,
                              hipStream_t stream) {
  const float* ego     = (const float*)d_in[0];
  const int*   A_rows  = (const int*)d_in[1];
  const int*   A_cols  = (const int*)d_in[2];
  const float* A_vals  = (const float*)d_in[3];
  const int*   p1_rows = (const int*)d_in[4];
  const int*   p1_cols = (const int*)d_in[5];
  const float* p1_vals = (const float*)d_in[6];
  const int*   p2_rows = (const int*)d_in[7];
  const int*   p2_cols = (const int*)d_in[8];
  const float* p2_vals = (const float*)d_in[9];
  const int*   l1_rows = (const int*)d_in[10];
  const int*   l1_cols = (const int*)d_in[11];
  const float* l1_vals = (const float*)d_in[12];
  const int*   l2_rows = (const int*)d_in[13];
  const int*   l2_cols = (const int*)d_in[14];
  const float* l2_vals = (const float*)d_in[15];
  const float* W1      = (const float*)d_in[16];
  const float* b1      = (const float*)d_in[17];
  const float* W2      = (const float*)d_in[18];
  const float* b2      = (const float*)d_in[19];

  const int nnz_A  = in_sizes[1];
  const int nnz_p1 = in_sizes[4];
  const int nnz_p2 = in_sizes[7];
  const int nnz_l1 = in_sizes[10];
  const int nnz_l2 = in_sizes[13];

  // --- workspace layout ---
  unsigned* egoh  = (unsigned*)d_ws;                 // N_ENT*64 u32 (bf16 pairs)
  unsigned* tmp1h = egoh + (size_t)N_ENT * 64;       // N_HE*64
  unsigned* tmp2h = tmp1h + (size_t)N_HE * 64;       // N_HE*64
  int2* cvA  = (int2*)(tmp2h + (size_t)N_HE * 64);   // nnz_A
  int2* cvp1 = cvA + nnz_A;
  int2* cvp2 = cvp1 + nnz_p1;
  int2* cvl1 = cvp2 + nnz_p2;
  int2* cvl2 = cvl1 + nnz_l1;
  int* curA  = (int*)(cvl2 + nnz_l2);                // N_ENT
  int* curp1 = curA + N_ENT;                         // N_HE
  int* curp2 = curp1 + N_HE;                         // N_ENT
  int* curl1 = curp2 + N_ENT;                        // N_HE
  int* curl2 = curl1 + N_HE;                         // N_ENT
  const size_t n_cur = 3 * (size_t)N_ENT + 2 * (size_t)N_HE;

  // Zero all counter arrays (contiguous), convert ego to bf16.
  hipMemsetAsync(curA, 0, n_cur * sizeof(int), stream);
  cvt_bf16_kernel<<<dim3(2048), dim3(256), 0, stream>>>(ego, egoh, N_ENT * (DIM / 4));

  // Fused CSR build.
  Seg5 sg;
  const int* rws[5]  = {A_rows, p1_rows, p2_rows, l1_rows, l2_rows};
  const int* cls[5]  = {A_cols, p1_cols, p2_cols, l1_cols, l2_cols};
  const float* vls[5] = {A_vals, p1_vals, p2_vals, l1_vals, l2_vals};
  int* crs[5]  = {curA, curp1, curp2, curl1, curl2};
  int2* cvs[5] = {cvA, cvp1, cvp2, cvl1, cvl2};
  const int nzs[5] = {nnz_A, nnz_p1, nnz_p2, nnz_l1, nnz_l2};
  int pfx = 0;
  for (int s = 0; s < 5; s++) {
    sg.rows[s] = rws[s]; sg.cols[s] = cls[s]; sg.vals[s] = vls[s];
    sg.cur[s] = crs[s];  sg.colv[s] = cvs[s];
    sg.blk_pfx[s] = pfx;
    pfx += (nzs[s] + 255) / 256;
  }
  sg.blk_pfx[5] = pfx;

  hist5_kernel<<<dim3(pfx), dim3(256), 0, stream>>>(sg, nnz_A, nnz_p1, nnz_p2, nnz_l1, nnz_l2);
  scan5_kernel<<<dim3(5), dim3(1024), 0, stream>>>(curA, N_ENT, curp1, N_HE,
                                                   curp2, N_ENT, curl1, N_HE,
                                                   curl2, N_ENT);
  scatter5_kernel<<<dim3(pfx), dim3(256), 0, stream>>>(sg, nnz_A, nnz_p1, nnz_p2, nnz_l1, nnz_l2);

  float* side = (float*)d_out;

  // Stage 1: both hyperedge aggregations, bf16 in/out.
  gather_he_kernel<<<dim3(N_HE / 8), dim3(256), 0, stream>>>(
      curp1, cvp1, curl1, cvl1, egoh, tmp1h, tmp2h);

  // Stage 2: side = A@ego + p2@tmp1 + l2@tmp2, fp32 write into d_out.
  gather_ent_kernel<<<dim3(N_ENT / 8), dim3(256), 0, stream>>>(
      curA, cvA, curp2, cvp2, curl2, cvl2, egoh, tmp1h, tmp2h, side);

  // Stage 3: fused bi-interaction epilogue (in-place on d_out).
  fused_epilogue_kernel<<<dim3((N_ENT + EROWS - 1) / EROWS), dim3(256), 0, stream>>>(
      ego, side, W1, b1, W2, b2);
}